// Round 12
// baseline (103.881 us; speedup 1.0000x reference)
//
#include <hip/hip_runtime.h>

#define B_SZ   256
#define T_SZ   512
#define EMB    128
#define HID    256
#define NCLS   32000

typedef __attribute__((ext_vector_type(8))) short short8;
typedef __attribute__((ext_vector_type(4))) float f32x4;

__device__ inline unsigned short bf16rne(float f) {
    union { float f; unsigned int u; } v; v.f = f;
    unsigned int u = v.u;
    u += 0x7FFFu + ((u >> 16) & 1u);
    return (unsigned short)(u >> 16);
}
__device__ inline unsigned pkhi(float lo, float hi) {
    union { float f; unsigned u; } a, b;
    a.f = lo; b.f = hi;
    return ((b.u + 0x8000u) & 0xFFFF0000u) | ((a.u + 0x8000u) >> 16);
}

// ---------------------------------------------------------------------------
// h is stored FRAG-MAJOR in d_ws: element (m,k) at
//   frag = (m>>4)*8 + (k>>5); lane = ((k>>3)&3)*16 + (m&15);
//   idx  = frag*512 + lane*8 + (k&7)
// Each B-fragment is a contiguous lane-linear 1 KB block: LDS staging is
// linear (no swizzle, rule 21), ds_read_b128 conflict-free (R7-proven).
// ---------------------------------------------------------------------------

// ---------------------------------------------------------------------------
// Kernel 1 (REWRITTEN this round): h_last for t = T-1 only (layer-0 state
// never updates; layer-1 scan discarded). 64 blocks x 4 m-rows x 256 thr.
// Each U element loaded once per block now feeds 4 FMAs (was 1 in R7-R11):
// U aggregate 96 -> 24 MB, VMEM instr count per output row / 4. 8 chunks
// of 48 pinned loads keep ~48 loads in flight against L2 latency.
// ---------------------------------------------------------------------------
__global__ __launch_bounds__(256)
void lstm_h_last(const int* __restrict__ X, const float* __restrict__ C_table,
                 const float* __restrict__ U_i, const float* __restrict__ b_i,
                 const float* __restrict__ U_c, const float* __restrict__ b_c,
                 const float* __restrict__ U_o, const float* __restrict__ b_o,
                 unsigned short* __restrict__ hws) {
    __shared__ float e[4][EMB];
    __shared__ int idx[4];
    const int t  = threadIdx.x;          // 0..255
    const int b4 = blockIdx.x * 4;

    if (t < 4) idx[t] = X[(size_t)(b4 + t) * T_SZ + (T_SZ - 1)];
    __syncthreads();
    #pragma unroll
    for (int p = 0; p < 2; ++p) {
        const int lin = p * 256 + t;
        e[lin >> 7][lin & 127] = C_table[(size_t)idx[lin >> 7] * EMB + (lin & 127)];
    }
    __syncthreads();

    const int k = t;                     // hidden index
    float ai[4] = {0.f,0.f,0.f,0.f}, ac[4] = {0.f,0.f,0.f,0.f}, ao[4] = {0.f,0.f,0.f,0.f};

    #pragma unroll
    for (int c = 0; c < 8; ++c) {        // 8 chunks x 16 ee
        float ui[16], uc[16], uo[16];
        #pragma unroll
        for (int j = 0; j < 16; ++j) {
            const int ee = c * 16 + j;
            ui[j] = U_i[ee * HID + k];
            uc[j] = U_c[ee * HID + k];
            uo[j] = U_o[ee * HID + k];
        }
        #pragma unroll
        for (int j = 0; j < 16; ++j)
            asm volatile("" : "+v"(ui[j]), "+v"(uc[j]), "+v"(uo[j]));
        #pragma unroll
        for (int j = 0; j < 16; ++j) {
            const int ee = c * 16 + j;
            #pragma unroll
            for (int r = 0; r < 4; ++r) {
                const float ev = e[r][ee];
                ai[r] += ev * ui[j]; ac[r] += ev * uc[j]; ao[r] += ev * uo[j];
            }
        }
    }

    #pragma unroll
    for (int r = 0; r < 4; ++r) {
        const int m = b4 + r;
        const float i0 = 1.f / (1.f + expf(-(ai[r] + b_i[k])));
        const float g0 = tanhf(ac[r] + b_c[k]);
        const float o0 = 1.f / (1.f + expf(-(ao[r] + b_o[k])));
        const unsigned short hv = bf16rne(o0 * tanhf(i0 * g0));
        const int frag = (m >> 4) * 8 + (k >> 5);
        const int li   = ((k >> 3) & 3) * 16 + (m & 15);
        hws[frag * 512 + li * 8 + (k & 7)] = hv;
    }
}

// ---------------------------------------------------------------------------
// Kernel 2: logits[m][n] = sum_k h[m][k]*W[n][k] + b_out[n].  M=256 N=32000
// K=256.  VERBATIM from R7 (best total, 30.1 us): one-shot, one barrier,
// W direct to regs (16 fully-coalesced dwordx4 per wave = its own 16-row
// n-stripe), h staged linearly to LDS via global_load_lds (frag-major,
// conflict-free), 128 MFMA, acc[16], stores at end.
// ---------------------------------------------------------------------------
__global__ __launch_bounds__(512, 2)
void logits_gemm(const unsigned short* __restrict__ hws,
                 const float* __restrict__ Ww,
                 const float* __restrict__ b_out,
                 float* __restrict__ out) {
    __shared__ unsigned short Hs[B_SZ * HID];   // 128 KB, frag-major linear

    const int t    = threadIdx.x;        // 0..511
    const int wid  = t >> 6;             // 0..7
    const int lane = t & 63;
    const int l15  = lane & 15;
    const int lq   = lane >> 4;          // 0..3

    const int nbase = blockIdx.x * 128 + wid * 16;

    // ---- 1. W loads: full K=256 stripe for this lane's n-row ----
    const float* wrow = Ww + (size_t)(nbase + l15) * HID + lq * 8;
    f32x4 wf[16];
    #pragma unroll
    for (int ks = 0; ks < 8; ++ks) {
        wf[2 * ks]     = *reinterpret_cast<const f32x4*>(wrow + ks * 32);
        wf[2 * ks + 1] = *reinterpret_cast<const f32x4*>(wrow + ks * 32 + 4);
    }

    // ---- 2. stage h slice [wid*16KB, +16KB): 16 x 1KB, fully linear ----
    #pragma unroll
    for (int j = 0; j < 16; ++j) {
        const unsigned short* src = hws + (wid * 16 + j) * 512;
        __builtin_amdgcn_global_load_lds(
            (const __attribute__((address_space(1))) unsigned int*)(src + lane * 8),
            (__attribute__((address_space(3))) unsigned int*)(Hs + (wid * 16 + j) * 512),
            16, 0, 0);
    }

    // ---- 3. pin W (forces materialization), drain, barrier ----
    #pragma unroll
    for (int i = 0; i < 16; ++i) asm volatile("" : "+v"(wf[i]));
    asm volatile("s_waitcnt vmcnt(0)" ::: "memory");
    __builtin_amdgcn_s_barrier();
    __builtin_amdgcn_sched_barrier(0);

    // ---- 4. convert W to bf16 A-fragments ----
    short8 aw[8];
    #pragma unroll
    for (int ks = 0; ks < 8; ++ks) {
        union { short8 s; unsigned u[4]; } p;
        p.u[0] = pkhi(wf[2 * ks][0],     wf[2 * ks][1]);
        p.u[1] = pkhi(wf[2 * ks][2],     wf[2 * ks][3]);
        p.u[2] = pkhi(wf[2 * ks + 1][0], wf[2 * ks + 1][1]);
        p.u[3] = pkhi(wf[2 * ks + 1][2], wf[2 * ks + 1][3]);
        aw[ks] = p.s;
    }

    f32x4 bv = *reinterpret_cast<const f32x4*>(b_out + nbase + lq * 4);

    // ---- MFMA: ks-outer -> 16 independent acc chains ----
    const unsigned short* hbase = Hs + lane * 8;
    f32x4 acc[16] = {};
    #pragma unroll
    for (int ks = 0; ks < 8; ++ks) {
        #pragma unroll
        for (int mf = 0; mf < 16; ++mf) {
            short8 bh = *reinterpret_cast<const short8*>(
                hbase + (mf * 8 + ks) * 512);
            acc[mf] = __builtin_amdgcn_mfma_f32_16x16x32_bf16(
                aw[ks], bh, acc[mf], 0, 0, 0);
        }
    }

    // ---- 5. epilogue: bias + stores ----
    #pragma unroll
    for (int mf = 0; mf < 16; ++mf) {
        f32x4 o = acc[mf] + bv;
        *reinterpret_cast<f32x4*>(
            out + (size_t)(mf * 16 + l15) * NCLS + nbase + lq * 4) = o;
    }
}

// ---------------------------------------------------------------------------
extern "C" void kernel_launch(void* const* d_in, const int* in_sizes, int n_in,
                              void* d_out, int out_size, void* d_ws, size_t ws_size,
                              hipStream_t stream) {
    const int*   X       = (const int*)  d_in[0];
    const float* C_table = (const float*)d_in[1];
    const float* U_i     = (const float*)d_in[2];
    const float* b_i     = (const float*)d_in[4];
    const float* U_c     = (const float*)d_in[8];
    const float* b_c     = (const float*)d_in[10];
    const float* U_o     = (const float*)d_in[11];
    const float* b_o     = (const float*)d_in[13];
    const float* W_w     = (const float*)d_in[26];
    const float* b_out   = (const float*)d_in[27];
    float* out = (float*)d_out;

    unsigned short* hws = (unsigned short*)d_ws;  // bf16 h_last, frag-major

    lstm_h_last<<<B_SZ / 4, 256, 0, stream>>>(X, C_table, U_i, b_i, U_c, b_c,
                                              U_o, b_o, hws);
    logits_gemm<<<NCLS / 128, 512, 0, stream>>>(hws, W_w, b_out, out);
}

// Round 13
// 27.960 us; speedup vs baseline: 3.7153x; 3.7153x over previous
//
#include <hip/hip_runtime.h>

#define B_SZ   256
#define T_SZ   512
#define EMB    128
#define HID    256
#define NCLS   32000

typedef __attribute__((ext_vector_type(8))) short short8;
typedef __attribute__((ext_vector_type(4))) float f32x4;

__device__ inline unsigned short bf16rne(float f) {
    union { float f; unsigned int u; } v; v.f = f;
    unsigned int u = v.u;
    u += 0x7FFFu + ((u >> 16) & 1u);
    return (unsigned short)(u >> 16);
}
__device__ inline unsigned pkhi(float lo, float hi) {
    union { float f; unsigned u; } a, b;
    a.f = lo; b.f = hi;
    return ((b.u + 0x8000u) & 0xFFFF0000u) | ((a.u + 0x8000u) >> 16);
}

// ---------------------------------------------------------------------------
// h is stored FRAG-MAJOR in d_ws: element (m,k) at
//   frag = (m>>4)*8 + (k>>5); lane = ((k>>3)&3)*16 + (m&15);
//   idx  = frag*512 + lane*8 + (k&7)
// Each B-fragment is a contiguous lane-linear 1 KB block: LDS staging in
// logits is linear (no swizzle, rule 21), ds_read_b128 conflict-free.
// ---------------------------------------------------------------------------

// ---------------------------------------------------------------------------
// Kernel 1 (REWRITTEN, anti-R12): h_last for t = T-1 only (layer-0 state
// never updates; layer-1 scan discarded).
// R12 failure: asm-pinned load batches + unroll -> VGPR=256 + 1.6KB/thread
// scratch spill (WRITE 25.6MB) at 1 wave/CU -> 95-122us.
// Now: 256 blocks x 1024 thr (16 waves/CU; launch_bounds(1024) forces
// VGPR<=128 so it cannot spill-or-die), thread = (k, ee-quarter) with
// 32 plain loop iterations x 3 loads, running scalars, NO pins, NO arrays.
// LDS reduce over the 4 quarters, q=0 waves do activations + store.
// ---------------------------------------------------------------------------
__global__ __launch_bounds__(1024)
void lstm_h_last(const int* __restrict__ X, const float* __restrict__ C_table,
                 const float* __restrict__ U_i, const float* __restrict__ b_i,
                 const float* __restrict__ U_c, const float* __restrict__ b_c,
                 const float* __restrict__ U_o, const float* __restrict__ b_o,
                 unsigned short* __restrict__ hws) {
    __shared__ float e[EMB];
    __shared__ float part[3][4][HID];    // 12 KB
    const int m = blockIdx.x;
    const int t = threadIdx.x;           // 0..1023
    const int k = t & 255;               // hidden index
    const int q = t >> 8;                // ee-quarter 0..3

    const int token = X[(size_t)m * T_SZ + (T_SZ - 1)];   // uniform -> s_load
    if (t < EMB) e[t] = C_table[(size_t)token * EMB + t];
    __syncthreads();

    float ai = 0.f, ac = 0.f, ao = 0.f;
    const int ee0 = q * 32;
    #pragma unroll
    for (int j = 0; j < 32; ++j) {
        const int ee = ee0 + j;
        const float ev = e[ee];                       // LDS broadcast (free)
        ai += ev * U_i[ee * HID + k];                 // 256B coalesced/wave
        ac += ev * U_c[ee * HID + k];
        ao += ev * U_o[ee * HID + k];
    }
    part[0][q][k] = ai;
    part[1][q][k] = ac;
    part[2][q][k] = ao;
    __syncthreads();

    if (q == 0) {
        const float si = part[0][0][k] + part[0][1][k] + part[0][2][k] + part[0][3][k];
        const float sc = part[1][0][k] + part[1][1][k] + part[1][2][k] + part[1][3][k];
        const float so = part[2][0][k] + part[2][1][k] + part[2][2][k] + part[2][3][k];
        const float i0 = 1.f / (1.f + expf(-(si + b_i[k])));
        const float g0 = tanhf(sc + b_c[k]);
        const float o0 = 1.f / (1.f + expf(-(so + b_o[k])));
        const unsigned short hv = bf16rne(o0 * tanhf(i0 * g0));
        const int frag = (m >> 4) * 8 + (k >> 5);
        const int li   = ((k >> 3) & 3) * 16 + (m & 15);
        hws[frag * 512 + li * 8 + (k & 7)] = hv;
    }
}

// ---------------------------------------------------------------------------
// Kernel 2: logits[m][n] = sum_k h[m][k]*W[n][k] + b_out[n].  M=256 N=32000
// K=256.  VERBATIM R7 (measured ~9-12us via R12 decomposition, at the
// 66MB/6.9TB/s BW floor): one-shot, one barrier, W direct to regs (16
// fully-coalesced dwordx4 per wave = its own 16-row n-stripe), h staged
// linearly to LDS via global_load_lds (frag-major, conflict-free),
// 128 MFMA, acc[16], stores at end.
// ---------------------------------------------------------------------------
__global__ __launch_bounds__(512, 2)
void logits_gemm(const unsigned short* __restrict__ hws,
                 const float* __restrict__ Ww,
                 const float* __restrict__ b_out,
                 float* __restrict__ out) {
    __shared__ unsigned short Hs[B_SZ * HID];   // 128 KB, frag-major linear

    const int t    = threadIdx.x;        // 0..511
    const int wid  = t >> 6;             // 0..7
    const int lane = t & 63;
    const int l15  = lane & 15;
    const int lq   = lane >> 4;          // 0..3

    const int nbase = blockIdx.x * 128 + wid * 16;

    // ---- 1. W loads: full K=256 stripe for this lane's n-row ----
    const float* wrow = Ww + (size_t)(nbase + l15) * HID + lq * 8;
    f32x4 wf[16];
    #pragma unroll
    for (int ks = 0; ks < 8; ++ks) {
        wf[2 * ks]     = *reinterpret_cast<const f32x4*>(wrow + ks * 32);
        wf[2 * ks + 1] = *reinterpret_cast<const f32x4*>(wrow + ks * 32 + 4);
    }

    // ---- 2. stage h slice [wid*16KB, +16KB): 16 x 1KB, fully linear ----
    #pragma unroll
    for (int j = 0; j < 16; ++j) {
        const unsigned short* src = hws + (wid * 16 + j) * 512;
        __builtin_amdgcn_global_load_lds(
            (const __attribute__((address_space(1))) unsigned int*)(src + lane * 8),
            (__attribute__((address_space(3))) unsigned int*)(Hs + (wid * 16 + j) * 512),
            16, 0, 0);
    }

    // ---- 3. pin W (forces materialization), drain, barrier ----
    #pragma unroll
    for (int i = 0; i < 16; ++i) asm volatile("" : "+v"(wf[i]));
    asm volatile("s_waitcnt vmcnt(0)" ::: "memory");
    __builtin_amdgcn_s_barrier();
    __builtin_amdgcn_sched_barrier(0);

    // ---- 4. convert W to bf16 A-fragments ----
    short8 aw[8];
    #pragma unroll
    for (int ks = 0; ks < 8; ++ks) {
        union { short8 s; unsigned u[4]; } p;
        p.u[0] = pkhi(wf[2 * ks][0],     wf[2 * ks][1]);
        p.u[1] = pkhi(wf[2 * ks][2],     wf[2 * ks][3]);
        p.u[2] = pkhi(wf[2 * ks + 1][0], wf[2 * ks + 1][1]);
        p.u[3] = pkhi(wf[2 * ks + 1][2], wf[2 * ks + 1][3]);
        aw[ks] = p.s;
    }

    f32x4 bv = *reinterpret_cast<const f32x4*>(b_out + nbase + lq * 4);

    // ---- MFMA: ks-outer -> 16 independent acc chains ----
    const unsigned short* hbase = Hs + lane * 8;
    f32x4 acc[16] = {};
    #pragma unroll
    for (int ks = 0; ks < 8; ++ks) {
        #pragma unroll
        for (int mf = 0; mf < 16; ++mf) {
            short8 bh = *reinterpret_cast<const short8*>(
                hbase + (mf * 8 + ks) * 512);
            acc[mf] = __builtin_amdgcn_mfma_f32_16x16x32_bf16(
                aw[ks], bh, acc[mf], 0, 0, 0);
        }
    }

    // ---- 5. epilogue: bias + stores ----
    #pragma unroll
    for (int mf = 0; mf < 16; ++mf) {
        f32x4 o = acc[mf] + bv;
        *reinterpret_cast<f32x4*>(
            out + (size_t)(mf * 16 + l15) * NCLS + nbase + lq * 4) = o;
    }
}

// ---------------------------------------------------------------------------
extern "C" void kernel_launch(void* const* d_in, const int* in_sizes, int n_in,
                              void* d_out, int out_size, void* d_ws, size_t ws_size,
                              hipStream_t stream) {
    const int*   X       = (const int*)  d_in[0];
    const float* C_table = (const float*)d_in[1];
    const float* U_i     = (const float*)d_in[2];
    const float* b_i     = (const float*)d_in[4];
    const float* U_c     = (const float*)d_in[8];
    const float* b_c     = (const float*)d_in[10];
    const float* U_o     = (const float*)d_in[11];
    const float* b_o     = (const float*)d_in[13];
    const float* W_w     = (const float*)d_in[26];
    const float* b_out   = (const float*)d_in[27];
    float* out = (float*)d_out;

    unsigned short* hws = (unsigned short*)d_ws;  // bf16 h_last, frag-major

    lstm_h_last<<<B_SZ, 1024, 0, stream>>>(X, C_table, U_i, b_i, U_c, b_c,
                                           U_o, b_o, hws);
    logits_gemm<<<NCLS / 128, 512, 0, stream>>>(hws, W_w, b_out, out);
}

// Round 14
// 27.868 us; speedup vs baseline: 3.7276x; 1.0033x over previous
//
#include <hip/hip_runtime.h>

#define B_SZ   256
#define T_SZ   512
#define EMB    128
#define HID    256
#define NCLS   32000

typedef __attribute__((ext_vector_type(8))) short short8;
typedef __attribute__((ext_vector_type(4))) float f32x4;

__device__ inline unsigned short bf16rne(float f) {
    union { float f; unsigned int u; } v; v.f = f;
    unsigned int u = v.u;
    u += 0x7FFFu + ((u >> 16) & 1u);
    return (unsigned short)(u >> 16);
}
__device__ inline unsigned pkhi(float lo, float hi) {
    union { float f; unsigned u; } a, b;
    a.f = lo; b.f = hi;
    return ((b.u + 0x8000u) & 0xFFFF0000u) | ((a.u + 0x8000u) >> 16);
}

// ---------------------------------------------------------------------------
// h is stored FRAG-MAJOR in d_ws: element (m,k) at
//   frag = (m>>4)*8 + (k>>5); lane = ((k>>3)&3)*16 + (m&15);
//   idx  = frag*512 + lane*8 + (k&7)
// Each B-fragment is a contiguous lane-linear 1 KB block: LDS staging in
// logits is linear (no swizzle, rule 21), ds_read_b128 conflict-free.
// ---------------------------------------------------------------------------

// ---------------------------------------------------------------------------
// Kernel 1 (REWRITTEN, anti-R12): h_last for t = T-1 only (layer-0 state
// never updates; layer-1 scan discarded).
// R12 failure: asm-pinned load batches + unroll -> VGPR=256 + 1.6KB/thread
// scratch spill (WRITE 25.6MB) at 1 wave/CU -> 95-122us.
// Now: 256 blocks x 1024 thr (16 waves/CU; launch_bounds(1024) forces
// VGPR<=128 so it cannot spill-or-die), thread = (k, ee-quarter) with
// 32 plain loop iterations x 3 loads, running scalars, NO pins, NO arrays.
// LDS reduce over the 4 quarters, q=0 waves do activations + store.
// ---------------------------------------------------------------------------
__global__ __launch_bounds__(1024)
void lstm_h_last(const int* __restrict__ X, const float* __restrict__ C_table,
                 const float* __restrict__ U_i, const float* __restrict__ b_i,
                 const float* __restrict__ U_c, const float* __restrict__ b_c,
                 const float* __restrict__ U_o, const float* __restrict__ b_o,
                 unsigned short* __restrict__ hws) {
    __shared__ float e[EMB];
    __shared__ float part[3][4][HID];    // 12 KB
    const int m = blockIdx.x;
    const int t = threadIdx.x;           // 0..1023
    const int k = t & 255;               // hidden index
    const int q = t >> 8;                // ee-quarter 0..3

    const int token = X[(size_t)m * T_SZ + (T_SZ - 1)];   // uniform -> s_load
    if (t < EMB) e[t] = C_table[(size_t)token * EMB + t];
    __syncthreads();

    float ai = 0.f, ac = 0.f, ao = 0.f;
    const int ee0 = q * 32;
    #pragma unroll
    for (int j = 0; j < 32; ++j) {
        const int ee = ee0 + j;
        const float ev = e[ee];                       // LDS broadcast (free)
        ai += ev * U_i[ee * HID + k];                 // 256B coalesced/wave
        ac += ev * U_c[ee * HID + k];
        ao += ev * U_o[ee * HID + k];
    }
    part[0][q][k] = ai;
    part[1][q][k] = ac;
    part[2][q][k] = ao;
    __syncthreads();

    if (q == 0) {
        const float si = part[0][0][k] + part[0][1][k] + part[0][2][k] + part[0][3][k];
        const float sc = part[1][0][k] + part[1][1][k] + part[1][2][k] + part[1][3][k];
        const float so = part[2][0][k] + part[2][1][k] + part[2][2][k] + part[2][3][k];
        const float i0 = 1.f / (1.f + expf(-(si + b_i[k])));
        const float g0 = tanhf(sc + b_c[k]);
        const float o0 = 1.f / (1.f + expf(-(so + b_o[k])));
        const unsigned short hv = bf16rne(o0 * tanhf(i0 * g0));
        const int frag = (m >> 4) * 8 + (k >> 5);
        const int li   = ((k >> 3) & 3) * 16 + (m & 15);
        hws[frag * 512 + li * 8 + (k & 7)] = hv;
    }
}

// ---------------------------------------------------------------------------
// Kernel 2: logits[m][n] = sum_k h[m][k]*W[n][k] + b_out[n].  M=256 N=32000
// K=256.  VERBATIM R7 (measured ~9-12us via R12 decomposition, at the
// 66MB/6.9TB/s BW floor): one-shot, one barrier, W direct to regs (16
// fully-coalesced dwordx4 per wave = its own 16-row n-stripe), h staged
// linearly to LDS via global_load_lds (frag-major, conflict-free),
// 128 MFMA, acc[16], stores at end.
// ---------------------------------------------------------------------------
__global__ __launch_bounds__(512, 2)
void logits_gemm(const unsigned short* __restrict__ hws,
                 const float* __restrict__ Ww,
                 const float* __restrict__ b_out,
                 float* __restrict__ out) {
    __shared__ unsigned short Hs[B_SZ * HID];   // 128 KB, frag-major linear

    const int t    = threadIdx.x;        // 0..511
    const int wid  = t >> 6;             // 0..7
    const int lane = t & 63;
    const int l15  = lane & 15;
    const int lq   = lane >> 4;          // 0..3

    const int nbase = blockIdx.x * 128 + wid * 16;

    // ---- 1. W loads: full K=256 stripe for this lane's n-row ----
    const float* wrow = Ww + (size_t)(nbase + l15) * HID + lq * 8;
    f32x4 wf[16];
    #pragma unroll
    for (int ks = 0; ks < 8; ++ks) {
        wf[2 * ks]     = *reinterpret_cast<const f32x4*>(wrow + ks * 32);
        wf[2 * ks + 1] = *reinterpret_cast<const f32x4*>(wrow + ks * 32 + 4);
    }

    // ---- 2. stage h slice [wid*16KB, +16KB): 16 x 1KB, fully linear ----
    #pragma unroll
    for (int j = 0; j < 16; ++j) {
        const unsigned short* src = hws + (wid * 16 + j) * 512;
        __builtin_amdgcn_global_load_lds(
            (const __attribute__((address_space(1))) unsigned int*)(src + lane * 8),
            (__attribute__((address_space(3))) unsigned int*)(Hs + (wid * 16 + j) * 512),
            16, 0, 0);
    }

    // ---- 3. pin W (forces materialization), drain, barrier ----
    #pragma unroll
    for (int i = 0; i < 16; ++i) asm volatile("" : "+v"(wf[i]));
    asm volatile("s_waitcnt vmcnt(0)" ::: "memory");
    __builtin_amdgcn_s_barrier();
    __builtin_amdgcn_sched_barrier(0);

    // ---- 4. convert W to bf16 A-fragments ----
    short8 aw[8];
    #pragma unroll
    for (int ks = 0; ks < 8; ++ks) {
        union { short8 s; unsigned u[4]; } p;
        p.u[0] = pkhi(wf[2 * ks][0],     wf[2 * ks][1]);
        p.u[1] = pkhi(wf[2 * ks][2],     wf[2 * ks][3]);
        p.u[2] = pkhi(wf[2 * ks + 1][0], wf[2 * ks + 1][1]);
        p.u[3] = pkhi(wf[2 * ks + 1][2], wf[2 * ks + 1][3]);
        aw[ks] = p.s;
    }

    f32x4 bv = *reinterpret_cast<const f32x4*>(b_out + nbase + lq * 4);

    // ---- MFMA: ks-outer -> 16 independent acc chains ----
    const unsigned short* hbase = Hs + lane * 8;
    f32x4 acc[16] = {};
    #pragma unroll
    for (int ks = 0; ks < 8; ++ks) {
        #pragma unroll
        for (int mf = 0; mf < 16; ++mf) {
            short8 bh = *reinterpret_cast<const short8*>(
                hbase + (mf * 8 + ks) * 512);
            acc[mf] = __builtin_amdgcn_mfma_f32_16x16x32_bf16(
                aw[ks], bh, acc[mf], 0, 0, 0);
        }
    }

    // ---- 5. epilogue: bias + stores ----
    #pragma unroll
    for (int mf = 0; mf < 16; ++mf) {
        f32x4 o = acc[mf] + bv;
        *reinterpret_cast<f32x4*>(
            out + (size_t)(mf * 16 + l15) * NCLS + nbase + lq * 4) = o;
    }
}

// ---------------------------------------------------------------------------
extern "C" void kernel_launch(void* const* d_in, const int* in_sizes, int n_in,
                              void* d_out, int out_size, void* d_ws, size_t ws_size,
                              hipStream_t stream) {
    const int*   X       = (const int*)  d_in[0];
    const float* C_table = (const float*)d_in[1];
    const float* U_i     = (const float*)d_in[2];
    const float* b_i     = (const float*)d_in[4];
    const float* U_c     = (const float*)d_in[8];
    const float* b_c     = (const float*)d_in[10];
    const float* U_o     = (const float*)d_in[11];
    const float* b_o     = (const float*)d_in[13];
    const float* W_w     = (const float*)d_in[26];
    const float* b_out   = (const float*)d_in[27];
    float* out = (float*)d_out;

    unsigned short* hws = (unsigned short*)d_ws;  // bf16 h_last, frag-major

    lstm_h_last<<<B_SZ, 1024, 0, stream>>>(X, C_table, U_i, b_i, U_c, b_c,
                                           U_o, b_o, hws);
    logits_gemm<<<NCLS / 128, 512, 0, stream>>>(hws, W_w, b_out, out);
}